// Round 1
// baseline (273.961 us; speedup 1.0000x reference)
//
#include <hip/hip_runtime.h>

#define T_STEPS 128
#define BATCH   2048
#define IN_F    64
#define HID     256
#define OUT_F   16

// Zero the spikes_mean accumulator slot (d_out is NOT re-poisoned between
// timed replays, and we accumulate into it with atomics -> must re-zero
// every call, ordered before the main kernel by stream semantics).
__global__ void snn_init_kernel(float* __restrict__ out) {
    if (threadIdx.x == 0 && blockIdx.x == 0) out[BATCH * OUT_F] = 0.0f;
}

// One block per batch row; thread = hidden neuron; all 128 timesteps fused.
__global__ void __launch_bounds__(256, 4)
snn_fused_kernel(const float* __restrict__ x,
                 const float* __restrict__ w1,
                 const float* __restrict__ w2,
                 float* __restrict__ out) {
    const int row  = blockIdx.x;
    const int tid  = threadIdx.x;
    const int lane = tid & 63;
    const int wv   = tid >> 6;
    const int o    = tid & 15;   // output index this thread contributes to (layer 2)
    const int c    = tid >> 4;   // 16-wide hidden chunk this thread covers (layer 2)

    __shared__ float zbuf[HID];
    __shared__ float wsum[4][OUT_F];
    __shared__ float sacc;
    if (tid == 0) sacc = 0.0f;

    const float dt_tau = (float)(0.001 * (1.0 / 0.006));   // 1/6
    const float decay  = (float)(1.0 - 0.001 * (1.0 / 0.006)); // 5/6

    // w1 row for this neuron -> 64 VGPRs (compile-time indices only)
    float wr[IN_F];
#pragma unroll
    for (int k = 0; k < IN_F; k += 4) {
        const float4 v = *reinterpret_cast<const float4*>(&w1[tid * IN_F + k]);
        wr[k] = v.x; wr[k + 1] = v.y; wr[k + 2] = v.z; wr[k + 3] = v.w;
    }
    // w2 fragment: output o, hidden chunk [16c, 16c+16) -> 16 VGPRs
    float w2r[16];
#pragma unroll
    for (int j = 0; j < 16; j += 4) {
        const float4 v = *reinterpret_cast<const float4*>(&w2[o * HID + c * 16 + j]);
        w2r[j] = v.x; w2r[j + 1] = v.y; w2r[j + 2] = v.z; w2r[j + 3] = v.w;
    }

    float v1 = 0.f, i1 = 0.f;                 // LIF state (this neuron)
    float v2 = 0.f, i2 = 0.f, ymax = -1e30f;  // LI state (wave0 lanes 0..15 only)
    float scnt = 0.f;                         // this neuron's spike count

    // x row pointer: block-uniform -> compiler scalarizes loads (s_load)
    const float* xp = x + (size_t)row * IN_F;

    for (int t = 0; t < T_STEPS; ++t) {
        // ---- layer 1: g1 = dot(x_t, w1[h]) over I=64, 4-way ILP ----
        float a0 = 0.f, a1 = 0.f, a2 = 0.f, a3 = 0.f;
#pragma unroll
        for (int k = 0; k < IN_F; k += 4) {
            a0 = fmaf(xp[k + 0], wr[k + 0], a0);
            a1 = fmaf(xp[k + 1], wr[k + 1], a1);
            a2 = fmaf(xp[k + 2], wr[k + 2], a2);
            a3 = fmaf(xp[k + 3], wr[k + 3], a3);
        }
        const float g1 = (a0 + a1) + (a2 + a3);

        // ---- LIF update (matches reference expression forms) ----
        const float v_dec = fmaf(dt_tau, i1 - v1, v1);  // v + dt_tau*(i - v)
        const float i_dec = i1 * decay;
        const bool  spk   = v_dec > 1.0f;               // heaviside(v_dec - 1)
        v1 = spk ? 0.0f : v_dec;
        i1 = i_dec + g1;
        const float z = spk ? 1.0f : 0.0f;
        scnt += z;
        zbuf[tid] = z;
        __syncthreads();   // A: z visible to layer-2 readers

        // ---- layer 2 partial: o = tid&15, hidden chunk c ----
        float p = 0.f;
#pragma unroll
        for (int j = 0; j < 16; ++j)
            p = fmaf(zbuf[c * 16 + j], w2r[j], p);
        // combine the 4 chunks living in this wave (lanes differ in bits 4,5)
        p += __shfl_xor(p, 16, 64);
        p += __shfl_xor(p, 32, 64);
        if (lane < 16) wsum[wv][lane] = p;
        __syncthreads();   // B: wave partials visible

        // ---- LI update + running max (wave0 lanes 0..15) ----
        if (tid < 16) {
            const float g2 = (wsum[0][tid] + wsum[1][tid]) +
                             (wsum[2][tid] + wsum[3][tid]);
            v2 = fmaf(dt_tau, i2 - v2, v2);
            i2 = i2 * decay + g2;
            ymax = fmaxf(ymax, v2);
        }
        xp += (size_t)BATCH * IN_F;
    }

    // score output for this row
    if (tid < 16) out[row * OUT_F + tid] = ymax;

    // spikes: wave reduce -> block reduce -> global atomic (exact: integers)
#pragma unroll
    for (int m = 1; m < 64; m <<= 1) scnt += __shfl_xor(scnt, m, 64);
    if (lane == 0) atomicAdd(&sacc, scnt);
    __syncthreads();
    if (tid == 0) atomicAdd(&out[BATCH * OUT_F], sacc * (1.0f / BATCH));
}

extern "C" void kernel_launch(void* const* d_in, const int* in_sizes, int n_in,
                              void* d_out, int out_size, void* d_ws, size_t ws_size,
                              hipStream_t stream) {
    const float* x  = (const float*)d_in[0];
    const float* w1 = (const float*)d_in[1];
    const float* w2 = (const float*)d_in[2];
    float* out = (float*)d_out;

    hipLaunchKernelGGL(snn_init_kernel, dim3(1), dim3(64), 0, stream, out);
    hipLaunchKernelGGL(snn_fused_kernel, dim3(BATCH), dim3(256), 0, stream,
                       x, w1, w2, out);
}